// Round 7
// baseline (323.326 us; speedup 1.0000x reference)
//
#include <hip/hip_runtime.h>

// Sorted-segment product: out[i] = prod_{j: csr[j]==i} x[ptrs[j]], empty -> 0.
//
// R11 = R10 with the nontemporal-load type fixed (native clang vector, not
// HIP_vector_type — the builtin rejects the latter). Theory unchanged:
//
// Established (R4-R9):
//   - fabric/L3 wall ~3.3-3.7 TB/s for gather traffic; time = traffic/wall.
//   - R9 (2x102us, 2x305MB): binned unconditional gather + exactly-resident
//     launches works; but x-refetch still 1.8x per-XCD compulsory (241MB vs
//     134MB per launch). Launch churn was NOT the main thrash source.
//   - Theory: the 64MB/launch ptrs+csr READ STREAM flows through the same
//     4MiB L2s and LRU-evicts x's ~2.5MB live window set. Every stream
//     byte is touched exactly once per launch -> caching it is pure loss.
// Fix:
//   (a) __builtin_nontemporal_load (gfx950 'nt') on ptrs staging and csr
//       product reads; x gather loads stay cached. Out stores left normal.
//   (b) NWIN 32 -> 64 (256KB windows): halves the drift live-set.

typedef int  i32x4 __attribute__((ext_vector_type(4)));   // native vector

#define EPT       16              // edges per thread
#define BLK       512             // threads per block (8 waves)
#define MSC       (BLK * EPT)     // 8192 edges per block
#define NWIN      64              // bins (256KB windows for N=2^22)
#define NPH       (MSC / BLK)     // 16 gather phases, 1 entry/thread each
#define NBLK      1024            // co-residency capacity: 4 blocks/CU

__global__ __launch_bounds__(BLK, 8) void prodseg_main(
    const float* __restrict__ x,
    const int*   __restrict__ ptrs,
    const int*   __restrict__ csr,
    float*       __restrict__ out,
    int E, int S, int wshift, int scbase, int F)
{
    __shared__ int      list[MSC];     // ptr, overwritten with value bits
    __shared__ unsigned hist[NWIN];
    __shared__ unsigned cursor[NWIN];
    __shared__ unsigned fs[BLK];       // first seg | (span ? 1<<31 : 0)
    __shared__ float    fp[BLK];       // first-run product

    const int sc = scbase + (int)blockIdx.x;
    if (sc >= F) return;               // block-uniform
    const int t = threadIdx.x;
    const int sbase = sc * MSC;
    const int gbase = sbase + t * EPT;

    if (t < NWIN) hist[t] = 0u;
    __syncthreads();

    // ---- stage my 16 ptrs (vectorized, 64B-aligned, non-temporal) ----
    int pt[EPT];
    {
        const i32x4* p4 = reinterpret_cast<const i32x4*>(ptrs + gbase);
        #pragma unroll
        for (int i = 0; i < EPT / 4; ++i) {
            i32x4 v = __builtin_nontemporal_load(p4 + i);
            pt[4*i+0] = v.x; pt[4*i+1] = v.y;
            pt[4*i+2] = v.z; pt[4*i+3] = v.w;
        }
    }

    // ---- histogram by window ----
    #pragma unroll
    for (int k = 0; k < EPT; ++k) {
        unsigned w = (unsigned)pt[k] >> wshift;
        w = w < NWIN ? w : NWIN - 1;
        atomicAdd(&hist[w], 1u);
    }
    __syncthreads();

    // ---- exclusive scan (NWIN values, thread 0) -> cursors ----
    if (t == 0) {
        unsigned acc = 0;
        #pragma unroll
        for (int w = 0; w < NWIN; ++w) { unsigned c = hist[w]; cursor[w] = acc; acc += c; }
    }
    __syncthreads();

    // ---- scatter ptrs into window-sorted list; keep my positions ----
    unsigned mp[EPT / 2];              // packed u16 pairs
    #pragma unroll
    for (int k = 0; k < EPT; ++k) {
        unsigned w = (unsigned)pt[k] >> wshift;
        w = w < NWIN ? w : NWIN - 1;
        unsigned pos = atomicAdd(&cursor[w], 1u);
        list[pos] = pt[k];
        if ((k & 1) == 0) mp[k >> 1] = pos;
        else              mp[k >> 1] |= pos << 16;
    }
    __syncthreads();

    // ---- phased gather over the window-sorted list (depth-2 pipeline) ----
    // Phase j: entry j*BLK + t. Unconditional, window-monotone. Consume
    // phase j-2's value while issuing phase j -> each load has two full
    // phases to land. Slot (m*BLK+t) is touched only by thread t between
    // barriers -> race-free; raw s_barrier paces waves (L2 locality), no
    // vmcnt drain.
    {
        int   pa = list[t];
        int   pb = list[BLK + t];
        float va = x[pa];              // phase 0 in flight
        float vb = x[pb];              // phase 1 in flight
        int   pc = list[2 * BLK + t];  // phase 2 ptr
        #pragma unroll
        for (int j = 2; j < NPH; ++j) {
            float vc = x[pc];                                  // issue phase j
            int pn = (j + 1 < NPH) ? list[(j + 1) * BLK + t] : 0;
            list[(j - 2) * BLK + t] = __float_as_int(va);      // consume j-2
            va = vb; vb = vc; pc = pn;
            __builtin_amdgcn_s_barrier();                      // pace, no drain
        }
        list[(NPH - 2) * BLK + t] = __float_as_int(va);
        list[(NPH - 1) * BLK + t] = __float_as_int(vb);
    }
    __syncthreads();                   // values visible to unbin (cross-thread)

    // ---- unbin my 16 values ----
    float g[EPT];
    #pragma unroll
    for (int k = 0; k < EPT; ++k) {
        unsigned pos = (k & 1) ? (mp[k >> 1] >> 16) : (mp[k >> 1] & 0xffffu);
        g[k] = __int_as_float(list[pos]);
    }

    // ---- product phase: local runs + first-run summary ----
    int prev = (gbase == 0) ? -1
                            : __builtin_nontemporal_load(csr + gbase - 1);
    const i32x4* c4 = reinterpret_cast<const i32x4*>(csr + gbase);
    int cur = 0; bool own = false, rec = false; float prod = 1.0f;
    #pragma unroll
    for (int i = 0; i < EPT / 4; ++i) {
        i32x4 c = __builtin_nontemporal_load(c4 + i);
        int sv[4] = {c.x, c.y, c.z, c.w};
        #pragma unroll
        for (int j = 0; j < 4; ++j) {
            const int k = 4 * i + j;
            int sg = sv[j];
            if (k == 0) {
                cur = sg; own = (sg != prev);
                prod = g[0];           // FULL head product (even if !own)
                if (own)
                    for (int q = prev + 1; q < cur; ++q) out[q] = 0.0f;
            } else if (sg == cur) {
                prod *= g[k];
            } else {
                if (!rec) { fs[t] = (unsigned)cur; fp[t] = prod; rec = true; }
                if (own) out[cur] = prod;
                for (int q = cur + 1; q < sg; ++q) out[q] = 0.0f;
                cur = sg; own = true; prod = g[k];
            }
        }
    }
    if (!rec) { fs[t] = (unsigned)cur | 0x80000000u; fp[t] = prod; }
    __syncthreads();

    // ---- tail walk over THREAD summaries (avg <1 step) ----
    if (own) {
        bool past = true;              // run continues past the block?
        for (int u = t + 1; u < BLK; ++u) {
            unsigned f = fs[u];
            if ((int)(f & 0x7fffffffu) != cur) { past = false; break; }
            prod *= fp[u];
            if (!(f & 0x80000000u)) { past = false; break; }
        }
        if (past) {
            // rare: run crosses the block boundary -> finish in global
            int idx = sbase + MSC;
            while (idx < E && csr[idx] == cur) { prod *= x[ptrs[idx]]; ++idx; }
            out[cur] = prod;
            if (idx == E)
                for (int q = cur + 1; q < S; ++q) out[q] = 0.0f;
        } else {
            out[cur] = prod;
        }
    }
}

// Generic tail (E % MSC != 0) — R1-proven logic; not launched for E = 2^24.
#define TK 8
__global__ __launch_bounds__(256) void prodseg_tail(
    const float* __restrict__ x,
    const int*   __restrict__ ptrs,
    const int*   __restrict__ csr,
    float*       __restrict__ out,
    int E0, int E, int S)
{
    int t = blockIdx.x * blockDim.x + threadIdx.x;
    int base = E0 + t * TK;
    if (base >= E) return;
    int prev = (base == 0) ? -1 : csr[base - 1];
    int n = (base + TK <= E) ? TK : (E - base);

    int cur = 0; bool own = false; float prod = 1.0f;
    for (int k = 0; k < n; ++k) {
        int sg = csr[base + k];
        float gv = x[ptrs[base + k]];
        if (k == 0) {
            cur = sg; own = (sg != prev);
            prod = own ? gv : 1.0f;
            if (own) for (int q = prev + 1; q < cur; ++q) out[q] = 0.0f;
        } else if (sg == cur) {
            prod *= gv;
        } else {
            if (own) out[cur] = prod;
            for (int q = cur + 1; q < sg; ++q) out[q] = 0.0f;
            cur = sg; own = true; prod = gv;
        }
    }
    if (own) {
        int idx = base + n;
        while (idx < E && csr[idx] == cur) { prod *= x[ptrs[idx]]; ++idx; }
        out[cur] = prod;
        if (idx == E) for (int q = cur + 1; q < S; ++q) out[q] = 0.0f;
    }
}

extern "C" void kernel_launch(void* const* d_in, const int* in_sizes, int n_in,
                              void* d_out, int out_size, void* d_ws, size_t ws_size,
                              hipStream_t stream) {
    const float* x    = (const float*)d_in[0];
    const int*   ptrs = (const int*)d_in[1];
    const int*   csr  = (const int*)d_in[2];
    float*       out  = (float*)d_out;
    int N = in_sizes[0];
    int E = in_sizes[1];
    int S = out_size;

    // smallest shift with (N-1)>>shift < NWIN (16 for N=2^22 -> 256KB windows)
    int wshift = 0;
    while (((unsigned)(N - 1) >> wshift) >= NWIN) ++wshift;

    int F  = E / MSC;                  // full blocks (2048 for E=2^24)
    int E0 = F * MSC;

    // Exactly-resident launches: each launch's 1024 blocks are all
    // co-resident (4/CU) and march the windows together; the inter-launch
    // dependency is a free grid barrier separating x-passes.
    for (int scbase = 0; scbase < F; scbase += NBLK) {
        int nb = F - scbase; if (nb > NBLK) nb = NBLK;
        prodseg_main<<<nb, BLK, 0, stream>>>(x, ptrs, csr, out, E, S,
                                             wshift, scbase, F);
    }
    if (E0 < E) {
        int nt = (E - E0 + TK - 1) / TK;
        prodseg_tail<<<(nt + 255) / 256, 256, 0, stream>>>(x, ptrs, csr, out, E0, E, S);
    }
}